// Round 1
// baseline (245.897 us; speedup 1.0000x reference)
//
#include <hip/hip_runtime.h>
#include <hip/hip_bf16.h>

#define N_HEADS 16
#define HEAD 64
#define B_SZ 2
#define T_SZ 2048
#define KD 1024
#define M_TOT (B_SZ * T_SZ)   // 4096

typedef short bf16x8 __attribute__((ext_vector_type(8)));
typedef float f32x4  __attribute__((ext_vector_type(4)));

__device__ __forceinline__ ushort f2bf(float f) {
    __hip_bfloat16 h = __float2bfloat16(f);
    return *reinterpret_cast<ushort*>(&h);
}

// ---------------- fp32 -> bf16 convert (vectorized) ----------------
__global__ void cvt_f32_bf16(const float* __restrict__ src, ushort* __restrict__ dst, int n4) {
    int i = blockIdx.x * blockDim.x + threadIdx.x;
    if (i < n4) {
        float4 v = reinterpret_cast<const float4*>(src)[i];
        ushort4 o;
        o.x = f2bf(v.x); o.y = f2bf(v.y); o.z = f2bf(v.z); o.w = f2bf(v.w);
        reinterpret_cast<ushort4*>(dst)[i] = o;
    }
}

// ---------------- GEMM: C[M,N] = A[M,K=1024] * B[N,K=1024]^T ----------------
// MODE 0: scatter-store bf16 into per-head Q/K/V layout (C = Qh base, K/V at fixed offsets)
// MODE 1: store fp32 to C (row-major [M,1024])
template<int MODE>
__global__ __launch_bounds__(256) void gemm_bt(const ushort* __restrict__ A,
                                               const ushort* __restrict__ Bm,
                                               void* __restrict__ Cv) {
    const int bm = blockIdx.x;
    const int bn = blockIdx.y;
    __shared__ ushort As[128][72];
    __shared__ ushort Bs[128][72];
    const int tid = threadIdx.x;
    const int lane = tid & 63;
    const int w = tid >> 6;
    const int wr = w >> 1, wc = w & 1;
    const int r15 = lane & 15, q4 = lane >> 4;

    f32x4 acc[4][4] = {};

    for (int k0 = 0; k0 < 1024; k0 += 64) {
        #pragma unroll
        for (int rep = 0; rep < 4; ++rep) {
            int r = (tid >> 3) + rep * 32;
            int c = (tid & 7) * 8;
            *(int4*)(&As[r][c]) = *(const int4*)(&A[(size_t)(bm * 128 + r) * 1024 + k0 + c]);
            *(int4*)(&Bs[r][c]) = *(const int4*)(&Bm[(size_t)(bn * 128 + r) * 1024 + k0 + c]);
        }
        __syncthreads();
        #pragma unroll
        for (int kk = 0; kk < 2; ++kk) {
            bf16x8 af[4], bfr[4];
            #pragma unroll
            for (int m = 0; m < 4; ++m)
                af[m] = *(const bf16x8*)(&As[wr * 64 + m * 16 + r15][kk * 32 + q4 * 8]);
            #pragma unroll
            for (int n = 0; n < 4; ++n)
                bfr[n] = *(const bf16x8*)(&Bs[wc * 64 + n * 16 + r15][kk * 32 + q4 * 8]);
            #pragma unroll
            for (int m = 0; m < 4; ++m)
                #pragma unroll
                for (int n = 0; n < 4; ++n)
                    acc[m][n] = __builtin_amdgcn_mfma_f32_16x16x32_bf16(af[m], bfr[n], acc[m][n], 0, 0, 0);
        }
        __syncthreads();
    }

    const int row0 = bm * 128 + wr * 64;
    const int col0 = bn * 128 + wc * 64;
    if (MODE == 0) {
        ushort* Qbase = (ushort*)Cv;   // Qh; Kh at +32*2048*64; Vh at +2x
        const size_t seg = (size_t)32 * 2048 * 64;
        #pragma unroll
        for (int m = 0; m < 4; ++m)
            #pragma unroll
            for (int n = 0; n < 4; ++n)
                #pragma unroll
                for (int i = 0; i < 4; ++i) {
                    int row = row0 + m * 16 + q4 * 4 + i;
                    int col = col0 + n * 16 + r15;
                    int which = col >> 10;
                    int rem = col & 1023;
                    int head = rem >> 6;
                    int d = rem & 63;
                    int bidx = row >> 11;
                    int t = row & 2047;
                    Qbase[which * seg + (((size_t)(bidx * 16 + head) * 2048 + t) * 64 + d)] =
                        f2bf(acc[m][n][i]);
                }
    } else {
        float* C = (float*)Cv;
        #pragma unroll
        for (int m = 0; m < 4; ++m)
            #pragma unroll
            for (int n = 0; n < 4; ++n)
                #pragma unroll
                for (int i = 0; i < 4; ++i) {
                    int row = row0 + m * 16 + q4 * 4 + i;
                    int col = col0 + n * 16 + r15;
                    C[(size_t)row * 1024 + col] = acc[m][n][i];
                }
    }
}

// ---------------- flash attention ----------------
// grid: (32 bh, 32 qtiles), 256 threads (4 waves, each wave owns 16 q-rows)
__global__ __launch_bounds__(256) void attn_fwd(const ushort* __restrict__ Qh,
                                                const ushort* __restrict__ Kh,
                                                const ushort* __restrict__ Vh,
                                                ushort* __restrict__ Ob) {
    const int bh = blockIdx.x;
    const int qt = blockIdx.y;
    const int tid = threadIdx.x;
    const int lane = tid & 63, w = tid >> 6;
    const int r15 = lane & 15, q4 = lane >> 4;

    const ushort* Qp = Qh + (size_t)bh * T_SZ * HEAD;
    const ushort* Kp = Kh + (size_t)bh * T_SZ * HEAD;
    const ushort* Vp = Vh + (size_t)bh * T_SZ * HEAD;

    __shared__ ushort Vt[64][72];        // transposed V tile: [d][kv]
    __shared__ ushort Pl[4][16][72];     // per-wave P bounce: [q][kv]

    const int qrow = qt * 64 + w * 16 + r15;
    bf16x8 qf0 = *(const bf16x8*)(&Qp[(size_t)qrow * 64 + q4 * 8]);
    bf16x8 qf1 = *(const bf16x8*)(&Qp[(size_t)qrow * 64 + 32 + q4 * 8]);

    float mrow[4] = {-1e30f, -1e30f, -1e30f, -1e30f};
    float lrow[4] = {0.f, 0.f, 0.f, 0.f};
    f32x4 acc[4] = {};

    for (int kv0 = 0; kv0 < T_SZ; kv0 += 64) {
        // stage V transposed
        #pragma unroll
        for (int rep = 0; rep < 2; ++rep) {
            int idx = tid + rep * 256;
            int kv = idx >> 3;
            int c = (idx & 7) * 8;
            bf16x8 vv = *(const bf16x8*)(&Vp[(size_t)(kv0 + kv) * 64 + c]);
            #pragma unroll
            for (int j = 0; j < 8; ++j) Vt[c + j][kv] = (ushort)vv[j];
        }
        __syncthreads();

        // S = Q K^T for 4 16-wide kv tiles
        f32x4 s[4];
        #pragma unroll
        for (int t4 = 0; t4 < 4; ++t4) {
            bf16x8 kf0 = *(const bf16x8*)(&Kp[(size_t)(kv0 + t4 * 16 + r15) * 64 + q4 * 8]);
            bf16x8 kf1 = *(const bf16x8*)(&Kp[(size_t)(kv0 + t4 * 16 + r15) * 64 + 32 + q4 * 8]);
            f32x4 z = {};
            z = __builtin_amdgcn_mfma_f32_16x16x32_bf16(qf0, kf0, z, 0, 0, 0);
            z = __builtin_amdgcn_mfma_f32_16x16x32_bf16(qf1, kf1, z, 0, 0, 0);
            s[t4] = z * 0.03125f;   // 1/sqrt(1024)
        }

        // online softmax (rows live across 16 lanes of the quarter)
        #pragma unroll
        for (int i = 0; i < 4; ++i) {
            float vm = fmaxf(fmaxf(s[0][i], s[1][i]), fmaxf(s[2][i], s[3][i]));
            #pragma unroll
            for (int d = 1; d < 16; d <<= 1) vm = fmaxf(vm, __shfl_xor(vm, d, 64));
            float mn = fmaxf(mrow[i], vm);
            float alpha = __expf(mrow[i] - mn);
            mrow[i] = mn;
            float rs = 0.f;
            #pragma unroll
            for (int t4 = 0; t4 < 4; ++t4) {
                float p = __expf(s[t4][i] - mn);
                s[t4][i] = p;
                rs += p;
            }
            #pragma unroll
            for (int d = 1; d < 16; d <<= 1) rs += __shfl_xor(rs, d, 64);
            lrow[i] = lrow[i] * alpha + rs;
            #pragma unroll
            for (int dt = 0; dt < 4; ++dt) acc[dt][i] *= alpha;
        }

        // P -> LDS (per-wave region), then PV
        #pragma unroll
        for (int t4 = 0; t4 < 4; ++t4)
            #pragma unroll
            for (int i = 0; i < 4; ++i)
                Pl[w][q4 * 4 + i][t4 * 16 + r15] = f2bf(s[t4][i]);

        #pragma unroll
        for (int kk2 = 0; kk2 < 2; ++kk2) {
            bf16x8 pf = *(const bf16x8*)(&Pl[w][r15][kk2 * 32 + q4 * 8]);
            #pragma unroll
            for (int dt = 0; dt < 4; ++dt) {
                bf16x8 vf = *(const bf16x8*)(&Vt[dt * 16 + r15][kk2 * 32 + q4 * 8]);
                acc[dt] = __builtin_amdgcn_mfma_f32_16x16x32_bf16(pf, vf, acc[dt], 0, 0, 0);
            }
        }
        __syncthreads();
    }

    // epilogue: O / l  -> Ob [b][t][1024] bf16
    const int b = bh >> 4, h = bh & 15;
    #pragma unroll
    for (int i = 0; i < 4; ++i) {
        int q = qt * 64 + w * 16 + q4 * 4 + i;
        float inv = 1.0f / lrow[i];
        #pragma unroll
        for (int dt = 0; dt < 4; ++dt) {
            int d = dt * 16 + r15;
            Ob[((size_t)(b * T_SZ + q)) * KD + h * HEAD + d] = f2bf(acc[dt][i] * inv);
        }
    }
}

extern "C" void kernel_launch(void* const* d_in, const int* in_sizes, int n_in,
                              void* d_out, int out_size, void* d_ws, size_t ws_size,
                              hipStream_t stream) {
    const float* x  = (const float*)d_in[0];
    const float* Wq = (const float*)d_in[1];
    const float* Wk = (const float*)d_in[2];
    const float* Wv = (const float*)d_in[3];
    const float* Wo = (const float*)d_in[4];

    char* ws = (char*)d_ws;
    const size_t MB = 1024 * 1024;
    ushort* xb    = (ushort*)(ws + 0);        // [4096][1024]       8 MB
    ushort* Wqkvb = (ushort*)(ws + 8  * MB);  // [3072][1024]       6 MB
    ushort* Wob   = (ushort*)(ws + 14 * MB);  // [1024][1024]       2 MB
    ushort* Qh    = (ushort*)(ws + 16 * MB);  // [32][2048][64]     8 MB
    ushort* Kh    = (ushort*)(ws + 24 * MB);
    ushort* Vh    = (ushort*)(ws + 32 * MB);
    ushort* Ob    = (ushort*)(ws + 40 * MB);  // [4096][1024]       8 MB

    // converts
    {
        int n4 = (M_TOT * KD) / 4;
        cvt_f32_bf16<<<(n4 + 255) / 256, 256, 0, stream>>>(x, xb, n4);
        n4 = (KD * KD) / 4;
        cvt_f32_bf16<<<(n4 + 255) / 256, 256, 0, stream>>>(Wq, Wqkvb, n4);
        cvt_f32_bf16<<<(n4 + 255) / 256, 256, 0, stream>>>(Wk, Wqkvb + KD * KD, n4);
        cvt_f32_bf16<<<(n4 + 255) / 256, 256, 0, stream>>>(Wv, Wqkvb + 2 * KD * KD, n4);
        cvt_f32_bf16<<<(n4 + 255) / 256, 256, 0, stream>>>(Wo, Wob, n4);
    }

    // fused QKV projection: [4096,3072] = xb * Wqkvb^T, scatter to Qh/Kh/Vh
    gemm_bt<0><<<dim3(32, 24), 256, 0, stream>>>(xb, Wqkvb, (void*)Qh);

    // attention
    attn_fwd<<<dim3(32, 32), 256, 0, stream>>>(Qh, Kh, Vh, Ob);

    // output projection -> fp32 out
    gemm_bt<1><<<dim3(32, 8), 256, 0, stream>>>(Ob, Wob, d_out);
}